// Round 11
// baseline (536.072 us; speedup 1.0000x reference)
//
#include <hip/hip_runtime.h>
#include <hip/hip_cooperative_groups.h>
#include <math.h>

namespace coop = cooperative_groups;

#define TT 2
#define CC 64
#define HH 160
#define WW 160
#define KS 7
#define K2 49
#define NSPIX 196
#define HWSZ (HH*WW)
#define PAD 3
#define OO 64
#define FANIN (CC*K2)
#define TS 8
#define PS (TS+KS-1)   // 14
#define NPOS (PS*PS)   // 196

#define NCHUNK 50
#define CHUNKPIX 512
#define NVB 800        // virtual blocks (tiles); real grid may be smaller

typedef _Float16 half8 __attribute__((ext_vector_type(8)));
typedef float f32x16 __attribute__((ext_vector_type(16)));
typedef unsigned int uint4v __attribute__((ext_vector_type(4)));
typedef _Float16 half2v __attribute__((ext_vector_type(2)));

__device__ __forceinline__ int reflect(int i, int n) {
    if (i < 0) i = -i;
    if (i >= n) i = 2*n - 2 - i;
    return i;
}

// ---------------- shared device helpers (used by both paths) ----------------

__device__ __forceinline__ void seg_unit(int u, int tid, const float* __restrict__ x,
                                         const int* __restrict__ spix,
                                         float* __restrict__ sums, float* __restrict__ cnts,
                                         float* ls, float* lcnt) {
    int cgi = u & 7;
    int rest = u >> 3;
    int ch = rest % NCHUNK;
    int t  = rest / NCHUNK;

    for (int i = tid; i < 8*200; i += 256) ls[i] = 0.f;
    if (cgi == 0) for (int i = tid; i < 200; i += 256) lcnt[i] = 0.f;
    __syncthreads();

    int base = ch*CHUNKPIX;
    const float* xb = x + ((size_t)t*CC + cgi*8)*HWSZ;
    #pragma unroll
    for (int i = 0; i < CHUNKPIX; i += 256) {
        int pix = base + i + tid;
        int s = spix[t*HWSZ + pix];
        if (cgi == 0) atomicAdd(&lcnt[s], 1.0f);
        #pragma unroll
        for (int j = 0; j < 8; ++j) atomicAdd(&ls[j*200 + s], xb[(size_t)j*HWSZ + pix]);
    }
    __syncthreads();

    float* sb = sums + (size_t)t*NSPIX*CC + cgi*8;
    for (int i = tid; i < 8*NSPIX; i += 256) {
        int s = i >> 3, j = i & 7;
        float v = ls[j*200 + s];
        if (v != 0.f) atomicAdd(&sb[s*CC + j], v);
    }
    if (cgi == 0)
        for (int i = tid; i < NSPIX; i += 256) {
            float v = lcnt[i];
            if (v != 0.f) atomicAdd(&cnts[t*NSPIX + i], v);
        }
    __syncthreads();
}

__device__ __forceinline__ void scale_unit(int u, int tid, const float* __restrict__ x,
                                           const float* __restrict__ wsc,
                                           const float* __restrict__ bsc,
                                           float* __restrict__ scale,
                                           _Float16* __restrict__ xT) {
    int pix = (u - 800)*256 + tid;       // < 51200 exactly
    int t = pix / HWSZ, hw = pix - t*HWSZ;
    const float* xs = x + (size_t)t*CC*HWSZ + hw;
    float s1 = 0.f, s2 = 0.f;
    unsigned int pk[32];
    #pragma unroll
    for (int cp = 0; cp < 32; ++cp) {
        float v0 = xs[(size_t)(2*cp)*HWSZ];
        float v1 = xs[(size_t)(2*cp + 1)*HWSZ];
        s1 += wsc[2*cp]*v0 + wsc[2*cp+1]*v1;
        s2 = fmaf(v0, v0, s2); s2 = fmaf(v1, v1, s2);
        half2v h; h[0] = (_Float16)v0; h[1] = (_Float16)v1;
        pk[cp] = __builtin_bit_cast(unsigned int, h);
    }
    float z = s1/(sqrtf(s2) + 1e-10f) + bsc[0];
    float sp_ = (z > 0.f) ? z + log1pf(expf(-z)) : log1pf(expf(z));
    scale[pix] = 10.f*sp_;
    uint4v* dst = (uint4v*)(xT + (size_t)pix*64);
    #pragma unroll
    for (int q = 0; q < 8; ++q) {
        uint4v v = { pk[4*q], pk[4*q+1], pk[4*q+2], pk[4*q+3] };
        dst[q] = v;
    }
}

__device__ __forceinline__ void wb_unit(int u, int tid, const float* __restrict__ Wl,
                                        _Float16* __restrict__ Wb) {
    int row = (u - 1000)*256 + tid;
    if (row < 2*K2*4*64) {
        int ln  = row & 63;
        int kc  = (row >> 6) & 3;
        int tq  = row >> 8;
        int tap = tq % K2;
        int qo  = tq / K2;
        int o = qo*32 + (ln & 31);
        int cb = kc*16 + (ln >> 5)*8;
        _Float16* dst = Wb + (size_t)row*8;
        const float* src = Wl + (size_t)o*FANIN + tap;
        #pragma unroll
        for (int j = 0; j < 8; ++j) dst[j] = (_Float16)src[(size_t)(cb + j)*K2];
    }
}

__device__ __forceinline__ void pwd_unit(int idx, const float* __restrict__ sums,
                                         const float* __restrict__ cnts,
                                         float* __restrict__ pwd) {
    int t = idx / (NSPIX*NSPIX); int r = idx - t*NSPIX*NSPIX;
    int s = r / NSPIX, uu = r - (r / NSPIX)*NSPIX;
    const float* ds = sums + (size_t)(t*NSPIX + s)*CC;
    const float* du = sums + (size_t)(t*NSPIX + uu)*CC;
    float is = 1.0f / fmaxf(cnts[t*NSPIX + s], 1.0f);
    float iu = 1.0f / fmaxf(cnts[t*NSPIX + uu], 1.0f);
    float acc = 0.f;
    #pragma unroll 8
    for (int c = 0; c < CC; ++c) {
        float d = ds[c]*is - du[c]*iu;
        acc = fmaf(d, d, acc);
    }
    pwd[idx] = acc;
}

// MFMA main tile body. smem must be >= 33424 B.
__device__ __forceinline__ void main_tile(int vb, int tid, char* smem,
    const _Float16* __restrict__ xT, const int* __restrict__ spix,
    const _Float16* __restrict__ Wb, const float* __restrict__ b_lin,
    const float* __restrict__ pwd, const float* __restrict__ scale,
    float* __restrict__ out)
{
    unsigned short* xpT = (unsigned short*)smem;            // 25088 B
    unsigned short* rwb = (unsigned short*)(smem + 25088);  // 6272 B
    int*   sp  = (int*)(smem + 31360);                      // 784 B
    float* mxp = (float*)(smem + 32144);                    // 1024 B
    float* mxl = (float*)(smem + 33168);                    // 256 B

    int t = vb / 400;
    int r = vb - t*400;
    int th0 = (r / 20)*TS, tw0 = (r - (r/20)*20)*TS;

    for (int i = tid; i < NPOS; i += 256) {
        int rr = reflect(th0 + i/PS - PAD, HH);
        int cc = reflect(tw0 + i%PS - PAD, WW);
        sp[i] = spix[t*HWSZ + rr*WW + cc];
    }
    {
        const _Float16* xt = xT + (size_t)t*HWSZ*64;
        for (int i = tid; i < NPOS*8; i += 256) {
            int pos = i >> 3, cb = i & 7;
            int rr = reflect(th0 + pos/PS - PAD, HH);
            int cc = reflect(tw0 + pos%PS - PAD, WW);
            uint4v v = *(const uint4v*)(xt + (size_t)(rr*WW + cc)*64 + cb*8);
            int chunk = cb ^ (pos & 7);
            *(uint4v*)&xpT[pos*64 + chunk*8] = v;
        }
    }
    __syncthreads();

    int p_ = tid & 63;
    int ty = tid >> 6;
    int py0 = p_ >> 3, px0 = p_ & 7;
    {
        float sc = scale[t*HWSZ + (th0 + py0)*WW + (tw0 + px0)];
        int s0 = sp[(py0 + PAD)*PS + (px0 + PAD)];
        const float* pr = pwd + (t*NSPIX + s0)*NSPIX;
        float pmax = 0.f;
        for (int k = ty; k < K2; k += 4) {
            int di = k/KS, dj = k - di*KS;
            int nb = sp[(py0 + di)*PS + (px0 + dj)];
            float v = expf(-sc * pr[nb]);
            rwb[k*64 + p_] = __builtin_bit_cast(unsigned short, (_Float16)v);
            pmax = fmaxf(pmax, v);
        }
        mxp[ty*64 + p_] = pmax;
    }
    __syncthreads();
    if (ty == 0) {
        float m = fmaxf(fmaxf(mxp[p_], mxp[64 + p_]), fmaxf(mxp[128 + p_], mxp[192 + p_]));
        mxl[p_] = 1.f/(1e-5f + m);
    }
    __syncthreads();
    {
        float s = mxl[p_];
        for (int k = ty; k < K2; k += 4) {
            float v = (float)__builtin_bit_cast(_Float16, rwb[k*64 + p_]) * s;
            rwb[k*64 + p_] = __builtin_bit_cast(unsigned short, (_Float16)v);
        }
    }
    __syncthreads();

    int ln = p_;
    int wv = __builtin_amdgcn_readfirstlane(ty);
    int qp = wv & 1, kh = wv >> 1;
    int p  = qp*32 + (ln & 31);
    int ppy = p >> 3, ppx = p & 7;
    int lhi = ln >> 5;

    int jc0 = 4*kh + lhi, jc1 = jc0 + 2;

    const _Float16* A0b = Wb + (size_t)(2*kh)*512 + ln*8;   // qo=0
    const _Float16* A1b = A0b + (size_t)K2*4*512;           // qo=1

    f32x16 acc0, acc1;
    #pragma unroll
    for (int i = 0; i < 16; ++i) { acc0[i] = 0.f; acc1[i] = 0.f; }

    int di = 0, dj = 0;
    #pragma unroll 7
    for (int tap = 0; tap < K2; ++tap) {
        const _Float16* a0 = A0b + (size_t)tap*2048;
        half8 A00 = *(const half8*)(a0);
        half8 A01 = *(const half8*)(a0 + 512);
        const _Float16* a1 = A1b + (size_t)tap*2048;
        half8 A10 = *(const half8*)(a1);
        half8 A11 = *(const half8*)(a1 + 512);

        int pos = (ppy + di)*PS + (ppx + dj);
        int sw  = pos & 7;
        const unsigned short* bbase = &xpT[pos*64];
        half8 B0 = *(const half8*)(bbase + ((jc0 ^ sw) << 3));
        half8 B1 = *(const half8*)(bbase + ((jc1 ^ sw) << 3));

        _Float16 rv = __builtin_bit_cast(_Float16, rwb[tap*64 + p]);
        half8 rv8 = { rv, rv, rv, rv, rv, rv, rv, rv };
        B0 *= rv8;
        B1 *= rv8;

        acc0 = __builtin_amdgcn_mfma_f32_32x32x16_f16(A00, B0, acc0, 0, 0, 0);
        acc0 = __builtin_amdgcn_mfma_f32_32x32x16_f16(A01, B1, acc0, 0, 0, 0);
        acc1 = __builtin_amdgcn_mfma_f32_32x32x16_f16(A10, B0, acc1, 0, 0, 0);
        acc1 = __builtin_amdgcn_mfma_f32_32x32x16_f16(A11, B1, acc1, 0, 0, 0);

        if (++dj == KS) { dj = 0; ++di; }
    }

    __syncthreads();
    float* red = (float*)xpT;
    if (kh == 1) {
        #pragma unroll
        for (int i = 0; i < 16; ++i) {
            red[((qp*2 + 0)*16 + i)*64 + ln] = acc0[i];
            red[((qp*2 + 1)*16 + i)*64 + ln] = acc1[i];
        }
    }
    __syncthreads();
    if (kh == 0) {
        int h = th0 + ppy, w = tw0 + ppx;
        int row_hi = 4*lhi;
        float* ob = out + (size_t)t*OO*HWSZ + h*WW + w;
        #pragma unroll
        for (int rg = 0; rg < 16; ++rg) {
            int o0 = (rg & 3) + 8*(rg >> 2) + row_hi;
            int o1 = 32 + o0;
            float v0 = acc0[rg] + red[((qp*2 + 0)*16 + rg)*64 + ln];
            float v1 = acc1[rg] + red[((qp*2 + 1)*16 + rg)*64 + ln];
            ob[(size_t)o0*HWSZ] = v0 + b_lin[o0];
            ob[(size_t)o1*HWSZ] = v1 + b_lin[o1];
        }
    }
    __syncthreads();   // red/rwb reused next virtual tile
}

// ---------------- cooperative single-dispatch kernel ----------------

__global__ __launch_bounds__(256, 4) void k_all(
    const float* __restrict__ x, const int* __restrict__ spix,
    const float* __restrict__ Wl, const float* __restrict__ b_lin,
    const float* __restrict__ wsc, const float* __restrict__ bsc,
    float* __restrict__ sums, float* __restrict__ cnts,
    float* __restrict__ pwd, float* __restrict__ scale,
    _Float16* __restrict__ Wb, _Float16* __restrict__ xT,
    float* __restrict__ out)
{
    __shared__ __align__(16) char smem[33440];
    coop::grid_group grid = coop::this_grid();

    int bid = blockIdx.x;
    int tid = threadIdx.y*64 + threadIdx.x;
    int stride = gridDim.x;

    // P0: zero sums+cnts
    for (int idx = bid*256 + tid; idx < TT*NSPIX*CC + TT*NSPIX; idx += stride*256)
        sums[idx] = 0.f;
    __threadfence_system();
    grid.sync();
    __threadfence_system();

    // P1: seg / scale+xT / Wb  (1196 units)
    for (int u = bid; u < 1196; u += stride) {
        if (u < 800)       seg_unit(u, tid, x, spix, sums, cnts, (float*)smem, (float*)smem + 8*200);
        else if (u < 1000) scale_unit(u, tid, x, wsc, bsc, scale, xT);
        else               wb_unit(u, tid, Wl, Wb);
    }
    __threadfence_system();
    grid.sync();
    __threadfence_system();

    // P2: pwd
    for (int idx = bid*256 + tid; idx < TT*NSPIX*NSPIX; idx += stride*256)
        pwd_unit(idx, sums, cnts, pwd);
    __threadfence_system();
    grid.sync();
    __threadfence_system();

    // P3: MFMA tiles (800 virtual)
    for (int vb = bid; vb < NVB; vb += stride)
        main_tile(vb, tid, smem, xT, spix, Wb, b_lin, pwd, scale, out);
}

// ---------------- fallback multi-dispatch kernels (R8, known good) ----------------

__global__ __launch_bounds__(256) void k_prep(const float* __restrict__ x,
                                              const int* __restrict__ spix,
                                              const float* __restrict__ Wl,
                                              const float* __restrict__ wsc,
                                              const float* __restrict__ bsc,
                                              float* __restrict__ sums,
                                              float* __restrict__ cnts,
                                              float* __restrict__ scale,
                                              _Float16* __restrict__ Wb,
                                              _Float16* __restrict__ xT) {
    __shared__ float ls[8*200 + 200];
    int bid = blockIdx.x;
    int tid = threadIdx.x;
    if (bid < 800)       seg_unit(bid, tid, x, spix, sums, cnts, ls, ls + 8*200);
    else if (bid < 1000) scale_unit(bid, tid, x, wsc, bsc, scale, xT);
    else                 wb_unit(bid, tid, Wl, Wb);
}

__global__ __launch_bounds__(256) void k_pwd(const float* __restrict__ sums,
                                             const float* __restrict__ cnts,
                                             float* __restrict__ pwd) {
    int idx = blockIdx.x*256 + threadIdx.x;
    if (idx < TT*NSPIX*NSPIX) pwd_unit(idx, sums, cnts, pwd);
}

__global__ __launch_bounds__(256, 4) void k_main(
    const _Float16* __restrict__ xT, const int* __restrict__ spix,
    const _Float16* __restrict__ Wb, const float* __restrict__ b_lin,
    const float* __restrict__ pwd, const float* __restrict__ scale,
    float* __restrict__ out)
{
    __shared__ __align__(16) char smem[33440];
    int tid = threadIdx.y*64 + threadIdx.x;
    main_tile(blockIdx.x, tid, smem, xT, spix, Wb, b_lin, pwd, scale, out);
}

// ---------------- host ----------------

extern "C" void kernel_launch(void* const* d_in, const int* in_sizes, int n_in,
                              void* d_out, int out_size, void* d_ws, size_t ws_size,
                              hipStream_t stream) {
    const float* x    = (const float*)d_in[0];
    const int*   spix = (const int*)d_in[1];
    const float* Wl   = (const float*)d_in[2];
    const float* bl   = (const float*)d_in[3];
    const float* wsc  = (const float*)d_in[4];
    const float* bsc  = (const float*)d_in[5];
    float* out = (float*)d_out;

    float* ws    = (float*)d_ws;
    float* sums  = ws;                           // 25088 f32
    float* cnts  = sums + TT*NSPIX*CC;           // 392
    float* pwd   = cnts + TT*NSPIX;              // 76832
    float* scale = pwd  + TT*NSPIX*NSPIX;        // 51200
    _Float16* Wb = (_Float16*)(scale + TT*HWSZ); // 200704 f16
    _Float16* xT = Wb + (size_t)2*K2*4*64*8;     // 3276800 f16 (6.55 MB)

    // capture-safe host queries: can we run cooperatively, and at what grid size?
    int coopAttr = 0;
    (void)hipDeviceGetAttribute(&coopAttr, hipDeviceAttributeCooperativeLaunch, 0);
    int blocksPerCU = 0;
    (void)hipOccupancyMaxActiveBlocksPerMultiprocessor(&blocksPerCU, k_all, 256, 0);

    bool coopOk = false;
    if (coopAttr && blocksPerCU > 0) {
        int nblk = blocksPerCU * 256;            // MI355X: 256 CUs
        if (nblk > NVB) nblk = NVB;
        void* args[] = { (void*)&x, (void*)&spix, (void*)&Wl, (void*)&bl,
                         (void*)&wsc, (void*)&bsc, (void*)&sums, (void*)&cnts,
                         (void*)&pwd, (void*)&scale, (void*)&Wb, (void*)&xT,
                         (void*)&out };
        hipError_t err = hipLaunchCooperativeKernel((void*)k_all, dim3(nblk),
                                                    dim3(64, 4, 1), args, 0, stream);
        coopOk = (err == hipSuccess);
    }

    if (!coopOk) {
        // R8 known-good multi-dispatch path
        hipMemsetAsync(sums, 0, (size_t)(TT*NSPIX*CC + TT*NSPIX)*sizeof(float), stream);
        k_prep<<<1196, 256, 0, stream>>>(x, spix, Wl, wsc, bsc, sums, cnts, scale, Wb, xT);
        k_pwd <<<(TT*NSPIX*NSPIX + 255)/256, 256, 0, stream>>>(sums, cnts, pwd);
        dim3 blk(64, 4, 1);
        k_main<<<TT*400, blk, 0, stream>>>(xT, spix, Wb, bl, pwd, scale, out);
    }
}

// Round 12
// 400.239 us; speedup vs baseline: 1.3394x; 1.3394x over previous
//
#include <hip/hip_runtime.h>
#include <hip/hip_cooperative_groups.h>
#include <math.h>

namespace coop = cooperative_groups;

#define TT 2
#define CC 64
#define HH 160
#define WW 160
#define KS 7
#define K2 49
#define NSPIX 196
#define HWSZ (HH*WW)
#define PAD 3
#define OO 64
#define FANIN (CC*K2)
#define TS 8
#define PS (TS+KS-1)   // 14
#define NPOS (PS*PS)   // 196

#define NCHUNK 50
#define CHUNKPIX 512
#define NVB 800        // virtual blocks (tiles); real grid may be smaller

typedef _Float16 half8 __attribute__((ext_vector_type(8)));
typedef float f32x16 __attribute__((ext_vector_type(16)));
typedef unsigned int uint4v __attribute__((ext_vector_type(4)));
typedef _Float16 half2v __attribute__((ext_vector_type(2)));

__device__ __forceinline__ int reflect(int i, int n) {
    if (i < 0) i = -i;
    if (i >= n) i = 2*n - 2 - i;
    return i;
}

// Cheap cross-XCD phase boundary: block's stores are drained to the local XCD
// L2 by __syncthreads (vmcnt(0) before s_barrier); ONE wave per block then does
// a device-scope wbl2/inv (release), grid.sync orders execution, one wave per
// block invalidates (acquire) so post-sync reads miss to the LLC.
// R11 used per-wave SYSTEM-scope fences: same semantics, ~20x the cost
// (WRITE_SIZE 57 MB vs 13 MB; k_all 650 us).
#define PHASE_BOUNDARY(grid, tid)            \
    do {                                     \
        __syncthreads();                     \
        if ((tid) < 64) __threadfence();     \
        (grid).sync();                       \
        if ((tid) < 64) __threadfence();     \
        __syncthreads();                     \
    } while (0)

// ---------------- shared device helpers (used by both paths) ----------------

__device__ __forceinline__ void seg_unit(int u, int tid, const float* __restrict__ x,
                                         const int* __restrict__ spix,
                                         float* __restrict__ sums, float* __restrict__ cnts,
                                         float* ls, float* lcnt) {
    int cgi = u & 7;
    int rest = u >> 3;
    int ch = rest % NCHUNK;
    int t  = rest / NCHUNK;

    for (int i = tid; i < 8*200; i += 256) ls[i] = 0.f;
    if (cgi == 0) for (int i = tid; i < 200; i += 256) lcnt[i] = 0.f;
    __syncthreads();

    int base = ch*CHUNKPIX;
    const float* xb = x + ((size_t)t*CC + cgi*8)*HWSZ;
    #pragma unroll
    for (int i = 0; i < CHUNKPIX; i += 256) {
        int pix = base + i + tid;
        int s = spix[t*HWSZ + pix];
        if (cgi == 0) atomicAdd(&lcnt[s], 1.0f);
        #pragma unroll
        for (int j = 0; j < 8; ++j) atomicAdd(&ls[j*200 + s], xb[(size_t)j*HWSZ + pix]);
    }
    __syncthreads();

    float* sb = sums + (size_t)t*NSPIX*CC + cgi*8;
    for (int i = tid; i < 8*NSPIX; i += 256) {
        int s = i >> 3, j = i & 7;
        float v = ls[j*200 + s];
        if (v != 0.f) atomicAdd(&sb[s*CC + j], v);
    }
    if (cgi == 0)
        for (int i = tid; i < NSPIX; i += 256) {
            float v = lcnt[i];
            if (v != 0.f) atomicAdd(&cnts[t*NSPIX + i], v);
        }
    __syncthreads();
}

__device__ __forceinline__ void scale_unit(int u, int tid, const float* __restrict__ x,
                                           const float* __restrict__ wsc,
                                           const float* __restrict__ bsc,
                                           float* __restrict__ scale,
                                           _Float16* __restrict__ xT) {
    int pix = (u - 800)*256 + tid;       // < 51200 exactly
    int t = pix / HWSZ, hw = pix - t*HWSZ;
    const float* xs = x + (size_t)t*CC*HWSZ + hw;
    float s1 = 0.f, s2 = 0.f;
    unsigned int pk[32];
    #pragma unroll
    for (int cp = 0; cp < 32; ++cp) {
        float v0 = xs[(size_t)(2*cp)*HWSZ];
        float v1 = xs[(size_t)(2*cp + 1)*HWSZ];
        s1 += wsc[2*cp]*v0 + wsc[2*cp+1]*v1;
        s2 = fmaf(v0, v0, s2); s2 = fmaf(v1, v1, s2);
        half2v h; h[0] = (_Float16)v0; h[1] = (_Float16)v1;
        pk[cp] = __builtin_bit_cast(unsigned int, h);
    }
    float z = s1/(sqrtf(s2) + 1e-10f) + bsc[0];
    float sp_ = (z > 0.f) ? z + log1pf(expf(-z)) : log1pf(expf(z));
    scale[pix] = 10.f*sp_;
    uint4v* dst = (uint4v*)(xT + (size_t)pix*64);
    #pragma unroll
    for (int q = 0; q < 8; ++q) {
        uint4v v = { pk[4*q], pk[4*q+1], pk[4*q+2], pk[4*q+3] };
        dst[q] = v;
    }
}

__device__ __forceinline__ void wb_unit(int u, int tid, const float* __restrict__ Wl,
                                        _Float16* __restrict__ Wb) {
    int row = (u - 1000)*256 + tid;
    if (row < 2*K2*4*64) {
        int ln  = row & 63;
        int kc  = (row >> 6) & 3;
        int tq  = row >> 8;
        int tap = tq % K2;
        int qo  = tq / K2;
        int o = qo*32 + (ln & 31);
        int cb = kc*16 + (ln >> 5)*8;
        _Float16* dst = Wb + (size_t)row*8;
        const float* src = Wl + (size_t)o*FANIN + tap;
        #pragma unroll
        for (int j = 0; j < 8; ++j) dst[j] = (_Float16)src[(size_t)(cb + j)*K2];
    }
}

__device__ __forceinline__ void pwd_unit(int idx, const float* __restrict__ sums,
                                         const float* __restrict__ cnts,
                                         float* __restrict__ pwd) {
    int t = idx / (NSPIX*NSPIX); int r = idx - t*NSPIX*NSPIX;
    int s = r / NSPIX, uu = r - (r / NSPIX)*NSPIX;
    const float* ds = sums + (size_t)(t*NSPIX + s)*CC;
    const float* du = sums + (size_t)(t*NSPIX + uu)*CC;
    float is = 1.0f / fmaxf(cnts[t*NSPIX + s], 1.0f);
    float iu = 1.0f / fmaxf(cnts[t*NSPIX + uu], 1.0f);
    float acc = 0.f;
    #pragma unroll 8
    for (int c = 0; c < CC; ++c) {
        float d = ds[c]*is - du[c]*iu;
        acc = fmaf(d, d, acc);
    }
    pwd[idx] = acc;
}

// MFMA main tile body. smem must be >= 33424 B.
__device__ __forceinline__ void main_tile(int vb, int tid, char* smem,
    const _Float16* __restrict__ xT, const int* __restrict__ spix,
    const _Float16* __restrict__ Wb, const float* __restrict__ b_lin,
    const float* __restrict__ pwd, const float* __restrict__ scale,
    float* __restrict__ out)
{
    unsigned short* xpT = (unsigned short*)smem;            // 25088 B
    unsigned short* rwb = (unsigned short*)(smem + 25088);  // 6272 B
    int*   sp  = (int*)(smem + 31360);                      // 784 B
    float* mxp = (float*)(smem + 32144);                    // 1024 B
    float* mxl = (float*)(smem + 33168);                    // 256 B

    int t = vb / 400;
    int r = vb - t*400;
    int th0 = (r / 20)*TS, tw0 = (r - (r/20)*20)*TS;

    for (int i = tid; i < NPOS; i += 256) {
        int rr = reflect(th0 + i/PS - PAD, HH);
        int cc = reflect(tw0 + i%PS - PAD, WW);
        sp[i] = spix[t*HWSZ + rr*WW + cc];
    }
    {
        const _Float16* xt = xT + (size_t)t*HWSZ*64;
        for (int i = tid; i < NPOS*8; i += 256) {
            int pos = i >> 3, cb = i & 7;
            int rr = reflect(th0 + pos/PS - PAD, HH);
            int cc = reflect(tw0 + pos%PS - PAD, WW);
            uint4v v = *(const uint4v*)(xt + (size_t)(rr*WW + cc)*64 + cb*8);
            int chunk = cb ^ (pos & 7);
            *(uint4v*)&xpT[pos*64 + chunk*8] = v;
        }
    }
    __syncthreads();

    int p_ = tid & 63;
    int ty = tid >> 6;
    int py0 = p_ >> 3, px0 = p_ & 7;
    {
        float sc = scale[t*HWSZ + (th0 + py0)*WW + (tw0 + px0)];
        int s0 = sp[(py0 + PAD)*PS + (px0 + PAD)];
        const float* pr = pwd + (t*NSPIX + s0)*NSPIX;
        float pmax = 0.f;
        for (int k = ty; k < K2; k += 4) {
            int di = k/KS, dj = k - di*KS;
            int nb = sp[(py0 + di)*PS + (px0 + dj)];
            float v = expf(-sc * pr[nb]);
            rwb[k*64 + p_] = __builtin_bit_cast(unsigned short, (_Float16)v);
            pmax = fmaxf(pmax, v);
        }
        mxp[ty*64 + p_] = pmax;
    }
    __syncthreads();
    if (ty == 0) {
        float m = fmaxf(fmaxf(mxp[p_], mxp[64 + p_]), fmaxf(mxp[128 + p_], mxp[192 + p_]));
        mxl[p_] = 1.f/(1e-5f + m);
    }
    __syncthreads();
    {
        float s = mxl[p_];
        for (int k = ty; k < K2; k += 4) {
            float v = (float)__builtin_bit_cast(_Float16, rwb[k*64 + p_]) * s;
            rwb[k*64 + p_] = __builtin_bit_cast(unsigned short, (_Float16)v);
        }
    }
    __syncthreads();

    int ln = p_;
    int wv = __builtin_amdgcn_readfirstlane(ty);
    int qp = wv & 1, kh = wv >> 1;
    int p  = qp*32 + (ln & 31);
    int ppy = p >> 3, ppx = p & 7;
    int lhi = ln >> 5;

    int jc0 = 4*kh + lhi, jc1 = jc0 + 2;

    const _Float16* A0b = Wb + (size_t)(2*kh)*512 + ln*8;   // qo=0
    const _Float16* A1b = A0b + (size_t)K2*4*512;           // qo=1

    f32x16 acc0, acc1;
    #pragma unroll
    for (int i = 0; i < 16; ++i) { acc0[i] = 0.f; acc1[i] = 0.f; }

    int di = 0, dj = 0;
    #pragma unroll 7
    for (int tap = 0; tap < K2; ++tap) {
        const _Float16* a0 = A0b + (size_t)tap*2048;
        half8 A00 = *(const half8*)(a0);
        half8 A01 = *(const half8*)(a0 + 512);
        const _Float16* a1 = A1b + (size_t)tap*2048;
        half8 A10 = *(const half8*)(a1);
        half8 A11 = *(const half8*)(a1 + 512);

        int pos = (ppy + di)*PS + (ppx + dj);
        int sw  = pos & 7;
        const unsigned short* bbase = &xpT[pos*64];
        half8 B0 = *(const half8*)(bbase + ((jc0 ^ sw) << 3));
        half8 B1 = *(const half8*)(bbase + ((jc1 ^ sw) << 3));

        _Float16 rv = __builtin_bit_cast(_Float16, rwb[tap*64 + p]);
        half8 rv8 = { rv, rv, rv, rv, rv, rv, rv, rv };
        B0 *= rv8;
        B1 *= rv8;

        acc0 = __builtin_amdgcn_mfma_f32_32x32x16_f16(A00, B0, acc0, 0, 0, 0);
        acc0 = __builtin_amdgcn_mfma_f32_32x32x16_f16(A01, B1, acc0, 0, 0, 0);
        acc1 = __builtin_amdgcn_mfma_f32_32x32x16_f16(A10, B0, acc1, 0, 0, 0);
        acc1 = __builtin_amdgcn_mfma_f32_32x32x16_f16(A11, B1, acc1, 0, 0, 0);

        if (++dj == KS) { dj = 0; ++di; }
    }

    __syncthreads();
    float* red = (float*)xpT;
    if (kh == 1) {
        #pragma unroll
        for (int i = 0; i < 16; ++i) {
            red[((qp*2 + 0)*16 + i)*64 + ln] = acc0[i];
            red[((qp*2 + 1)*16 + i)*64 + ln] = acc1[i];
        }
    }
    __syncthreads();
    if (kh == 0) {
        int h = th0 + ppy, w = tw0 + ppx;
        int row_hi = 4*lhi;
        float* ob = out + (size_t)t*OO*HWSZ + h*WW + w;
        #pragma unroll
        for (int rg = 0; rg < 16; ++rg) {
            int o0 = (rg & 3) + 8*(rg >> 2) + row_hi;
            int o1 = 32 + o0;
            float v0 = acc0[rg] + red[((qp*2 + 0)*16 + rg)*64 + ln];
            float v1 = acc1[rg] + red[((qp*2 + 1)*16 + rg)*64 + ln];
            ob[(size_t)o0*HWSZ] = v0 + b_lin[o0];
            ob[(size_t)o1*HWSZ] = v1 + b_lin[o1];
        }
    }
    __syncthreads();   // red/rwb reused next virtual tile
}

// ---------------- cooperative single-dispatch kernel ----------------

__global__ __launch_bounds__(256, 4) void k_all(
    const float* __restrict__ x, const int* __restrict__ spix,
    const float* __restrict__ Wl, const float* __restrict__ b_lin,
    const float* __restrict__ wsc, const float* __restrict__ bsc,
    float* __restrict__ sums, float* __restrict__ cnts,
    float* __restrict__ pwd, float* __restrict__ scale,
    _Float16* __restrict__ Wb, _Float16* __restrict__ xT,
    float* __restrict__ out)
{
    __shared__ __align__(16) char smem[33440];
    coop::grid_group grid = coop::this_grid();

    int bid = blockIdx.x;
    int tid = threadIdx.y*64 + threadIdx.x;
    int stride = gridDim.x;

    // P0: zero sums+cnts
    for (int idx = bid*256 + tid; idx < TT*NSPIX*CC + TT*NSPIX; idx += stride*256)
        sums[idx] = 0.f;
    PHASE_BOUNDARY(grid, tid);

    // P1: seg / scale+xT / Wb  (1196 units)
    for (int u = bid; u < 1196; u += stride) {
        if (u < 800)       seg_unit(u, tid, x, spix, sums, cnts, (float*)smem, (float*)smem + 8*200);
        else if (u < 1000) scale_unit(u, tid, x, wsc, bsc, scale, xT);
        else               wb_unit(u, tid, Wl, Wb);
    }
    PHASE_BOUNDARY(grid, tid);

    // P2: pwd
    for (int idx = bid*256 + tid; idx < TT*NSPIX*NSPIX; idx += stride*256)
        pwd_unit(idx, sums, cnts, pwd);
    PHASE_BOUNDARY(grid, tid);

    // P3: MFMA tiles (800 virtual)
    for (int vb = bid; vb < NVB; vb += stride)
        main_tile(vb, tid, smem, xT, spix, Wb, b_lin, pwd, scale, out);
}

// ---------------- fallback multi-dispatch kernels (R8, known good) ----------------

__global__ __launch_bounds__(256) void k_prep(const float* __restrict__ x,
                                              const int* __restrict__ spix,
                                              const float* __restrict__ Wl,
                                              const float* __restrict__ wsc,
                                              const float* __restrict__ bsc,
                                              float* __restrict__ sums,
                                              float* __restrict__ cnts,
                                              float* __restrict__ scale,
                                              _Float16* __restrict__ Wb,
                                              _Float16* __restrict__ xT) {
    __shared__ float ls[8*200 + 200];
    int bid = blockIdx.x;
    int tid = threadIdx.x;
    if (bid < 800)       seg_unit(bid, tid, x, spix, sums, cnts, ls, ls + 8*200);
    else if (bid < 1000) scale_unit(bid, tid, x, wsc, bsc, scale, xT);
    else                 wb_unit(bid, tid, Wl, Wb);
}

__global__ __launch_bounds__(256) void k_pwd(const float* __restrict__ sums,
                                             const float* __restrict__ cnts,
                                             float* __restrict__ pwd) {
    int idx = blockIdx.x*256 + threadIdx.x;
    if (idx < TT*NSPIX*NSPIX) pwd_unit(idx, sums, cnts, pwd);
}

__global__ __launch_bounds__(256, 4) void k_main(
    const _Float16* __restrict__ xT, const int* __restrict__ spix,
    const _Float16* __restrict__ Wb, const float* __restrict__ b_lin,
    const float* __restrict__ pwd, const float* __restrict__ scale,
    float* __restrict__ out)
{
    __shared__ __align__(16) char smem[33440];
    int tid = threadIdx.y*64 + threadIdx.x;
    main_tile(blockIdx.x, tid, smem, xT, spix, Wb, b_lin, pwd, scale, out);
}

// ---------------- host ----------------

extern "C" void kernel_launch(void* const* d_in, const int* in_sizes, int n_in,
                              void* d_out, int out_size, void* d_ws, size_t ws_size,
                              hipStream_t stream) {
    const float* x    = (const float*)d_in[0];
    const int*   spix = (const int*)d_in[1];
    const float* Wl   = (const float*)d_in[2];
    const float* bl   = (const float*)d_in[3];
    const float* wsc  = (const float*)d_in[4];
    const float* bsc  = (const float*)d_in[5];
    float* out = (float*)d_out;

    float* ws    = (float*)d_ws;
    float* sums  = ws;                           // 25088 f32
    float* cnts  = sums + TT*NSPIX*CC;           // 392
    float* pwd   = cnts + TT*NSPIX;              // 76832
    float* scale = pwd  + TT*NSPIX*NSPIX;        // 51200
    _Float16* Wb = (_Float16*)(scale + TT*HWSZ); // 200704 f16
    _Float16* xT = Wb + (size_t)2*K2*4*64*8;     // 3276800 f16 (6.55 MB)

    int coopAttr = 0;
    (void)hipDeviceGetAttribute(&coopAttr, hipDeviceAttributeCooperativeLaunch, 0);
    int blocksPerCU = 0;
    (void)hipOccupancyMaxActiveBlocksPerMultiprocessor(&blocksPerCU, k_all, 256, 0);

    bool coopOk = false;
    if (coopAttr && blocksPerCU > 0) {
        int nblk = blocksPerCU * 256;            // MI355X: 256 CUs
        if (nblk > NVB) nblk = NVB;
        void* args[] = { (void*)&x, (void*)&spix, (void*)&Wl, (void*)&bl,
                         (void*)&wsc, (void*)&bsc, (void*)&sums, (void*)&cnts,
                         (void*)&pwd, (void*)&scale, (void*)&Wb, (void*)&xT,
                         (void*)&out };
        hipError_t err = hipLaunchCooperativeKernel((void*)k_all, dim3(nblk),
                                                    dim3(64, 4, 1), args, 0, stream);
        coopOk = (err == hipSuccess);
    }

    if (!coopOk) {
        // R8 known-good multi-dispatch path
        hipMemsetAsync(sums, 0, (size_t)(TT*NSPIX*CC + TT*NSPIX)*sizeof(float), stream);
        k_prep<<<1196, 256, 0, stream>>>(x, spix, Wl, wsc, bsc, sums, cnts, scale, Wb, xT);
        k_pwd <<<(TT*NSPIX*NSPIX + 255)/256, 256, 0, stream>>>(sums, cnts, pwd);
        dim3 blk(64, 4, 1);
        k_main<<<TT*400, blk, 0, stream>>>(xT, spix, Wb, bl, pwd, scale, out);
    }
}

// Round 13
// 155.803 us; speedup vs baseline: 3.4407x; 2.5689x over previous
//
#include <hip/hip_runtime.h>
#include <math.h>

#define TT 2
#define CC 64
#define HH 160
#define WW 160
#define KS 7
#define K2 49
#define NSPIX 196
#define HWSZ (HH*WW)
#define PAD 3
#define OO 64
#define FANIN (CC*K2)
#define TS 8
#define PS (TS+KS-1)   // 14
#define NPOS (PS*PS)   // 196
#define XROW 72        // f16 per xpT row: 144 B stride -> banks rotate 4/row (conflict-free)

#define NCHUNK 50
#define CHUNKPIX 512

typedef _Float16 half8 __attribute__((ext_vector_type(8)));
typedef float f32x16 __attribute__((ext_vector_type(16)));
typedef unsigned int uint4v __attribute__((ext_vector_type(4)));
typedef _Float16 half2v __attribute__((ext_vector_type(2)));

__device__ __forceinline__ int reflect(int i, int n) {
    if (i < 0) i = -i;
    if (i >= n) i = 2*n - 2 - i;
    return i;
}

// fused prep: [0,800) seg (LDS accumulate + atomic flush to sums/cnts);
//             [800,1000) scale + xT (f16 transposed) emit; [1000,1196) Wb (f16) build
__global__ __launch_bounds__(256) void k_prep(const float* __restrict__ x,
                                              const int* __restrict__ spix,
                                              const float* __restrict__ Wl,
                                              const float* __restrict__ wsc,
                                              const float* __restrict__ bsc,
                                              float* __restrict__ sums,
                                              float* __restrict__ cnts,
                                              float* __restrict__ scale,
                                              _Float16* __restrict__ Wb,
                                              _Float16* __restrict__ xT) {
    __shared__ float ls[8*200];
    __shared__ float lcnt[200];
    int bid = blockIdx.x;
    int tid = threadIdx.x;

    if (bid < 800) {
        int cg = bid & 7;
        int rest = bid >> 3;
        int ch = rest % NCHUNK;
        int t  = rest / NCHUNK;

        for (int i = tid; i < 8*200; i += 256) ls[i] = 0.f;
        if (cg == 0) for (int i = tid; i < 200; i += 256) lcnt[i] = 0.f;
        __syncthreads();

        int base = ch*CHUNKPIX;
        const float* xb = x + ((size_t)t*CC + cg*8)*HWSZ;
        #pragma unroll
        for (int i = 0; i < CHUNKPIX; i += 256) {
            int pix = base + i + tid;
            int s = spix[t*HWSZ + pix];
            if (cg == 0) atomicAdd(&lcnt[s], 1.0f);
            #pragma unroll
            for (int j = 0; j < 8; ++j) atomicAdd(&ls[j*200 + s], xb[(size_t)j*HWSZ + pix]);
        }
        __syncthreads();

        float* sb = sums + (size_t)t*NSPIX*CC + cg*8;
        for (int i = tid; i < 8*NSPIX; i += 256) {
            int s = i >> 3, j = i & 7;
            float v = ls[j*200 + s];
            if (v != 0.f) atomicAdd(&sb[s*CC + j], v);
        }
        if (cg == 0)
            for (int i = tid; i < NSPIX; i += 256) {
                float v = lcnt[i];
                if (v != 0.f) atomicAdd(&cnts[t*NSPIX + i], v);
            }
    } else if (bid < 1000) {
        int pix = (bid - 800)*256 + tid;
        int t = pix / HWSZ, hw = pix - t*HWSZ;
        const float* xs = x + (size_t)t*CC*HWSZ + hw;
        float s1 = 0.f, s2 = 0.f;
        unsigned int pk[32];
        #pragma unroll
        for (int cp = 0; cp < 32; ++cp) {
            float v0 = xs[(size_t)(2*cp)*HWSZ];
            float v1 = xs[(size_t)(2*cp + 1)*HWSZ];
            s1 += wsc[2*cp]*v0 + wsc[2*cp+1]*v1;
            s2 = fmaf(v0, v0, s2); s2 = fmaf(v1, v1, s2);
            half2v h; h[0] = (_Float16)v0; h[1] = (_Float16)v1;
            pk[cp] = __builtin_bit_cast(unsigned int, h);
        }
        float z = s1/(sqrtf(s2) + 1e-10f) + bsc[0];
        float sp_ = (z > 0.f) ? z + log1pf(expf(-z)) : log1pf(expf(z));
        scale[pix] = 10.f*sp_;
        uint4v* dst = (uint4v*)(xT + (size_t)pix*64);
        #pragma unroll
        for (int q = 0; q < 8; ++q) {
            uint4v v = { pk[4*q], pk[4*q+1], pk[4*q+2], pk[4*q+3] };
            dst[q] = v;
        }
    } else {
        int row = (bid - 1000)*256 + tid;
        if (row < 2*K2*4*64) {
            int ln  = row & 63;
            int kc  = (row >> 6) & 3;
            int tq  = row >> 8;
            int tap = tq % K2;
            int qo  = tq / K2;
            int o = qo*32 + (ln & 31);
            int cb = kc*16 + (ln >> 5)*8;
            _Float16* dst = Wb + (size_t)row*8;
            const float* src = Wl + (size_t)o*FANIN + tap;
            #pragma unroll
            for (int j = 0; j < 8; ++j) dst[j] = (_Float16)src[(size_t)(cb + j)*K2];
        }
    }
}

// pwd directly from sums/cnts
__global__ __launch_bounds__(256) void k_pwd(const float* __restrict__ sums,
                                             const float* __restrict__ cnts,
                                             float* __restrict__ pwd) {
    int tid = blockIdx.x*256 + threadIdx.x;
    if (tid >= TT*NSPIX*NSPIX) return;
    int t = tid / (NSPIX*NSPIX); int r = tid - t*NSPIX*NSPIX;
    int s = r / NSPIX, u = r - (r / NSPIX)*NSPIX;
    const float* ds = sums + (size_t)(t*NSPIX + s)*CC;
    const float* du = sums + (size_t)(t*NSPIX + u)*CC;
    float is = 1.0f / fmaxf(cnts[t*NSPIX + s], 1.0f);
    float iu = 1.0f / fmaxf(cnts[t*NSPIX + u], 1.0f);
    float acc = 0.f;
    #pragma unroll 8
    for (int c = 0; c < CC; ++c) {
        float d = ds[c]*is - du[c]*iu;
        acc = fmaf(d, d, acc);
    }
    pwd[tid] = acc;
}

// MFMA main. Block = 8x8 pixel tile, 4 waves = (qo = wv&1, kh = wv>>1).
// Each wave: its kc-pair, its o-half, BOTH pixel groups -> every W-fragment
// read exactly once per block (A-L2 traffic 1x). xpT row stride 72 f16
// (144 B): banks rotate 4/row, so same-chunk lanes (Delta-pos 14/28/42) land
// on banks +24/+16/+8 -> conflict-free b128 reads (128 B stride was 4-way).
__global__ __launch_bounds__(256, 4) void k_main(
    const _Float16* __restrict__ xT, const int* __restrict__ spix,
    const _Float16* __restrict__ Wb, const float* __restrict__ b_lin,
    const float* __restrict__ pwd, const float* __restrict__ scale,
    float* __restrict__ out)
{
    __shared__ unsigned short xpT[NPOS*XROW];  // 28224 B, swizzled, stride 144 B
    __shared__ unsigned short rwb[K2*64];      // 6272 B (f16)
    __shared__ int   sp[NPOS];                 // 784 B
    __shared__ float mxp[4*64];                // 1024 B
    __shared__ float mxl[64];                  // 256 B

    int bid = blockIdx.x;
    int t = bid / 400;
    int r = bid - t*400;
    int th0 = (r / 20)*TS, tw0 = (r - (r/20)*20)*TS;
    int tid = threadIdx.y*64 + threadIdx.x;

    for (int i = tid; i < NPOS; i += 256) {
        int rr = reflect(th0 + i/PS - PAD, HH);
        int cc = reflect(tw0 + i%PS - PAD, WW);
        sp[i] = spix[t*HWSZ + rr*WW + cc];
    }
    // stage xpT from xT: coalesced 16B loads, XOR-swizzled 16B-chunk writes
    {
        const _Float16* xt = xT + (size_t)t*HWSZ*64;
        for (int i = tid; i < NPOS*8; i += 256) {
            int pos = i >> 3, cb = i & 7;
            int rr = reflect(th0 + pos/PS - PAD, HH);
            int cc = reflect(tw0 + pos%PS - PAD, WW);
            uint4v v = *(const uint4v*)(xt + (size_t)(rr*WW + cc)*64 + cb*8);
            int chunk = cb ^ (pos & 7);
            *(uint4v*)&xpT[pos*XROW + chunk*8] = v;
        }
    }
    __syncthreads();

    // rw build (f16, normalized per pixel)
    int p_ = threadIdx.x;
    int ty = threadIdx.y;
    int py0 = p_ >> 3, px0 = p_ & 7;
    {
        float sc = scale[t*HWSZ + (th0 + py0)*WW + (tw0 + px0)];
        int s0 = sp[(py0 + PAD)*PS + (px0 + PAD)];
        const float* pr = pwd + (t*NSPIX + s0)*NSPIX;
        float pmax = 0.f;
        for (int k = ty; k < K2; k += 4) {
            int di = k/KS, dj = k - di*KS;
            int nb = sp[(py0 + di)*PS + (px0 + dj)];
            float v = expf(-sc * pr[nb]);
            rwb[k*64 + p_] = __builtin_bit_cast(unsigned short, (_Float16)v);
            pmax = fmaxf(pmax, v);
        }
        mxp[ty*64 + p_] = pmax;
    }
    __syncthreads();
    if (ty == 0) {
        float m = fmaxf(fmaxf(mxp[p_], mxp[64 + p_]), fmaxf(mxp[128 + p_], mxp[192 + p_]));
        mxl[p_] = 1.f/(1e-5f + m);
    }
    __syncthreads();
    {
        float s = mxl[p_];
        for (int k = ty; k < K2; k += 4) {
            float v = (float)__builtin_bit_cast(_Float16, rwb[k*64 + p_]) * s;
            rwb[k*64 + p_] = __builtin_bit_cast(unsigned short, (_Float16)v);
        }
    }
    __syncthreads();

    int ln = threadIdx.x;
    int wv = __builtin_amdgcn_readfirstlane(threadIdx.y);
    int qo = wv & 1, kh = wv >> 1;
    int lhi = ln >> 5;
    int l31 = ln & 31;
    int p0 = l31, p1 = 32 + l31;          // both pixel groups
    int ppy0 = p0 >> 3, ppx0 = p0 & 7;    // pg1: ppy0+4, same ppx -> pos1 = pos0 + 56

    int jc0 = 4*kh + lhi, jc1 = jc0 + 2;

    const _Float16* Ab = Wb + ((size_t)(qo*K2*4) + 2*kh)*512 + ln*8;

    f32x16 acc0, acc1;
    #pragma unroll
    for (int i = 0; i < 16; ++i) { acc0[i] = 0.f; acc1[i] = 0.f; }

    int di = 0, dj = 0;
    #pragma unroll 7
    for (int tap = 0; tap < K2; ++tap) {
        const _Float16* a = Ab + (size_t)tap*2048;
        half8 A0 = *(const half8*)(a);
        half8 A1 = *(const half8*)(a + 512);

        int pos0 = (ppy0 + di)*PS + (ppx0 + dj);
        int sw   = pos0 & 7;                 // pos1 = pos0+56, 56&7==0 -> same sw
        const unsigned short* b0 = &xpT[pos0*XROW];
        const unsigned short* b1 = b0 + 56*XROW;
        half8 B00 = *(const half8*)(b0 + ((jc0 ^ sw) << 3));
        half8 B01 = *(const half8*)(b0 + ((jc1 ^ sw) << 3));
        half8 B10 = *(const half8*)(b1 + ((jc0 ^ sw) << 3));
        half8 B11 = *(const half8*)(b1 + ((jc1 ^ sw) << 3));

        _Float16 rv0 = __builtin_bit_cast(_Float16, rwb[tap*64 + p0]);
        _Float16 rv1 = __builtin_bit_cast(_Float16, rwb[tap*64 + p1]);
        half8 rv08 = { rv0, rv0, rv0, rv0, rv0, rv0, rv0, rv0 };
        half8 rv18 = { rv1, rv1, rv1, rv1, rv1, rv1, rv1, rv1 };
        B00 *= rv08;
        B01 *= rv08;
        B10 *= rv18;
        B11 *= rv18;

        acc0 = __builtin_amdgcn_mfma_f32_32x32x16_f16(A0, B00, acc0, 0, 0, 0);
        acc0 = __builtin_amdgcn_mfma_f32_32x32x16_f16(A1, B01, acc0, 0, 0, 0);
        acc1 = __builtin_amdgcn_mfma_f32_32x32x16_f16(A0, B10, acc1, 0, 0, 0);
        acc1 = __builtin_amdgcn_mfma_f32_32x32x16_f16(A1, B11, acc1, 0, 0, 0);

        if (++dj == KS) { dj = 0; ++di; }
    }

    // cross-kh reduction (reuse xpT as f32 buffer: (qo,pg,reg) x 64 lanes = 16 KB)
    __syncthreads();
    float* red = (float*)xpT;
    if (kh == 1) {
        #pragma unroll
        for (int i = 0; i < 16; ++i) {
            red[((qo*2 + 0)*16 + i)*64 + ln] = acc0[i];
            red[((qo*2 + 1)*16 + i)*64 + ln] = acc1[i];
        }
    }
    __syncthreads();
    if (kh == 0) {
        int h0 = th0 + ppy0, w0 = tw0 + ppx0;
        int row_hi = 4*lhi;
        float* ob0 = out + (size_t)t*OO*HWSZ + h0*WW + w0;
        float* ob1 = ob0 + 4*WW;   // pg1: h0+4, same w
        #pragma unroll
        for (int rg = 0; rg < 16; ++rg) {
            int o = qo*32 + (rg & 3) + 8*(rg >> 2) + row_hi;
            float v0 = acc0[rg] + red[((qo*2 + 0)*16 + rg)*64 + ln];
            float v1 = acc1[rg] + red[((qo*2 + 1)*16 + rg)*64 + ln];
            float bl = b_lin[o];
            ob0[(size_t)o*HWSZ] = v0 + bl;
            ob1[(size_t)o*HWSZ] = v1 + bl;
        }
    }
}

extern "C" void kernel_launch(void* const* d_in, const int* in_sizes, int n_in,
                              void* d_out, int out_size, void* d_ws, size_t ws_size,
                              hipStream_t stream) {
    const float* x    = (const float*)d_in[0];
    const int*   spix = (const int*)d_in[1];
    const float* Wl   = (const float*)d_in[2];
    const float* bl   = (const float*)d_in[3];
    const float* wsc  = (const float*)d_in[4];
    const float* bsc  = (const float*)d_in[5];
    float* out = (float*)d_out;

    float* ws    = (float*)d_ws;
    float* sums  = ws;                           // 25088 f32
    float* cnts  = sums + TT*NSPIX*CC;           // 392
    float* pwd   = cnts + TT*NSPIX;              // 76832
    float* scale = pwd  + TT*NSPIX*NSPIX;        // 51200
    _Float16* Wb = (_Float16*)(scale + TT*HWSZ); // 200704 f16
    _Float16* xT = Wb + (size_t)2*K2*4*64*8;     // 3276800 f16 (6.55 MB)

    hipMemsetAsync(sums, 0, (size_t)(TT*NSPIX*CC + TT*NSPIX)*sizeof(float), stream);

    k_prep<<<1196, 256, 0, stream>>>(x, spix, Wl, wsc, bsc, sums, cnts, scale, Wb, xT);
    k_pwd <<<(TT*NSPIX*NSPIX + 255)/256, 256, 0, stream>>>(sums, cnts, pwd);

    dim3 blk(64, 4, 1);
    k_main<<<TT*400, blk, 0, stream>>>(xT, spix, Wb, bl, pwd, scale, out);
}